// Round 16
// baseline (186.811 us; speedup 1.0000x reference)
//
#include <hip/hip_runtime.h>
#include <stdint.h>
#include <stddef.h>

// Problem geometry (B=4, S=2048, DIN=4096, DOUT=4096)
constexpr int MDIM = 8192;   // B*S
constexpr int NDIM = 4096;   // DOUT
constexpr int KDIM = 4096;   // DIN

using f32x4 = __attribute__((ext_vector_type(4))) float;
using s16x4 = __attribute__((ext_vector_type(4))) short;
using i32x4 = __attribute__((ext_vector_type(4))) int;

__device__ __forceinline__ short f32_to_bf16_rn(float f) {
  union { float f; uint32_t u; } v; v.f = f;
  uint32_t r = (v.u + 0x7FFFu + ((v.u >> 16) & 1u)) >> 16;  // RTN-even
  return (short)(uint16_t)r;
}

// ---------------- prepass 1: x f32 -> i8, per-row symmetric scale (row-major) ----
__global__ void __launch_bounds__(256) quant_x_kernel(const float* __restrict__ in,
                                                      signed char* __restrict__ out,
                                                      float* __restrict__ sx) {
  const int row = blockIdx.x;
  const int t   = threadIdx.x;
  const float* rp = in + (size_t)row * KDIM;
  f32x4 v[4];
  float m = 0.0f;
#pragma unroll
  for (int j = 0; j < 4; ++j) {
    v[j] = *(const f32x4*)(rp + t * 16 + j * 4);
#pragma unroll
    for (int e = 0; e < 4; ++e) m = fmaxf(m, __builtin_fabsf(v[j][e]));
  }
#pragma unroll
  for (int off = 32; off > 0; off >>= 1) m = fmaxf(m, __shfl_xor(m, off, 64));
  __shared__ float wmax[4];
  const int wv = t >> 6, ln = t & 63;
  if (ln == 0) wmax[wv] = m;
  __syncthreads();
  m = fmaxf(fmaxf(wmax[0], wmax[1]), fmaxf(wmax[2], wmax[3]));
  const float inv = (m > 0.0f) ? (127.0f / m) : 0.0f;
  if (t == 0) sx[row] = m * (1.0f / 127.0f);
  i32x4 o;
#pragma unroll
  for (int j = 0; j < 4; ++j) {
    int b[4];
#pragma unroll
    for (int e = 0; e < 4; ++e) {
      int q = (int)rintf(v[j][e] * inv);
      q = q < -127 ? -127 : (q > 127 ? 127 : q);
      b[e] = q & 255;
    }
    o[j] = b[0] | (b[1] << 8) | (b[2] << 16) | (b[3] << 24);
  }
  *(i32x4*)(out + (size_t)row * KDIM + t * 16) = o;
}

// ---------------- prepass 2: weight int32 -> i8 (exact, low-byte pack) ----------------
__global__ void __launch_bounds__(256) quant_w_kernel(const int* __restrict__ in,
                                                      signed char* __restrict__ out, int n16) {
  int i = blockIdx.x * 256 + threadIdx.x;
  const int stride = gridDim.x * 256;
  for (; i < n16; i += stride) {
    const i32x4* p = (const i32x4*)(in + (size_t)i * 16);
    i32x4 o;
#pragma unroll
    for (int j = 0; j < 4; ++j) {
      i32x4 a = p[j];
      o[j] = (a[0] & 255) | ((a[1] & 255) << 8) | ((a[2] & 255) << 16) | ((a[3] & 255) << 24);
    }
    *(i32x4*)(out + (size_t)i * 16) = o;
  }
}

// =====================================================================
// 256x256 i8 GEMM, 4-wave/128x128-wave-tile ring pipeline + T19 interleave.
//   out = (i32 acc) * sx[row] * s_w + bias[col]
// Rationale (r15 post-mortem): MFMA pipes are per-SIMD (4 parallel) but
// the LDS unit is CU-shared. 4 waves with 128x128 tiles cut shared-LDS
// reads per window 96->64 wave-b128 (each frag read feeds 4x the output),
// making the window MFMA-dominant (1305 cyc/SIMD vs 1024 LDS).
//
// LDS = 4 rotating buffers x 32 KB (A 16 KB @ +0, B 16 KB @ +16384),
// regions [256 rows][64 B]; round-3/8-proven zero-conflict laneoff and
// inverse-swizzled stage decode (slot o holds a = o ^ (((o>>9)&1)<<5)).
// 256 threads: thread t stages 8x16B = rows {r0,r0+64,r0+128,r0+192} x A,B.
//
// Window t (buf u=t&3, frag sets E/O by t&1):
//   { ds_read 16 frags(t+1) from buf[(t+1)&3] ; 8 GLL stage t+3 ;
//     64 MFMA (8x8, frags(t)) ; vmcnt(8) ; BAR }
// Ledger (8 GLL/thread/window): end-of-t outstanding {t+3:8, t+2:8} ->
//   vmcnt(8) retires stage(t+2); +BAR => buf[(t+2)&3] valid for window
//   t+1's reads. WAR: buf staged at t last read at t-2 (>=2 barriers).
// Prologue: stage 0,1,2 (24 GLL); vmcnt(16); BAR; read frags(0);
//   vmcnt(8); BAR.  Tail: t=60 last stage; t=61 vmcnt(0); t>=62 none.
// T19: sched_group_barrier pins 8 x {2 DS_READ, 1 VMEM_READ, 8 MFMA}.
// =====================================================================

#define BAR asm volatile("s_barrier" ::: "memory")
#define WAITVM(n) asm volatile("s_waitcnt vmcnt(" #n ")" ::: "memory")
#define SGB(mask, n) __builtin_amdgcn_sched_group_barrier((mask), (n), 0)

#define GLL(src, dst) __builtin_amdgcn_global_load_lds(                     \
    (const __attribute__((address_space(1))) void*)(src),                   \
    (__attribute__((address_space(3))) void*)(dst), 16, 0, 0)

// prologue: stage tile tau into buf tau (tau = 0,1,2); 8 GLL/thread.
#define STGP(tau) do {                                                      \
  GLL(Arow + (size_t)r0 * 4096 + (tau) * 64 + cb,                           \
      lds + (tau) * 32768 + t * 16);                                        \
  GLL(Arow + (size_t)(r0 + 64) * 4096 + (tau) * 64 + cb,                    \
      lds + (tau) * 32768 + 4096 + t * 16);                                 \
  GLL(Arow + (size_t)(r0 + 128) * 4096 + (tau) * 64 + cb,                   \
      lds + (tau) * 32768 + 8192 + t * 16);                                 \
  GLL(Arow + (size_t)(r0 + 192) * 4096 + (tau) * 64 + cb,                   \
      lds + (tau) * 32768 + 12288 + t * 16);                                \
  GLL(Brow + (size_t)r0 * 4096 + (tau) * 64 + cb,                           \
      lds + (tau) * 32768 + 16384 + t * 16);                                \
  GLL(Brow + (size_t)(r0 + 64) * 4096 + (tau) * 64 + cb,                    \
      lds + (tau) * 32768 + 16384 + 4096 + t * 16);                         \
  GLL(Brow + (size_t)(r0 + 128) * 4096 + (tau) * 64 + cb,                   \
      lds + (tau) * 32768 + 16384 + 8192 + t * 16);                         \
  GLL(Brow + (size_t)(r0 + 192) * 4096 + (tau) * 64 + cb,                   \
      lds + (tau) * 32768 + 16384 + 12288 + t * 16);                        \
} while (0)

// in-loop: 8 advancing per-thread source pointers (start at tile 3 cols)
#define STGL(u3) do {                                                       \
  GLL(aP0, lds + (u3) * 32768 + t * 16);                                    \
  GLL(aP1, lds + (u3) * 32768 + 4096 + t * 16);                             \
  GLL(aP2, lds + (u3) * 32768 + 8192 + t * 16);                             \
  GLL(aP3, lds + (u3) * 32768 + 12288 + t * 16);                            \
  GLL(bP0, lds + (u3) * 32768 + 16384 + t * 16);                            \
  GLL(bP1, lds + (u3) * 32768 + 16384 + 4096 + t * 16);                     \
  GLL(bP2, lds + (u3) * 32768 + 16384 + 8192 + t * 16);                     \
  GLL(bP3, lds + (u3) * 32768 + 16384 + 12288 + t * 16);                    \
  aP0 += 64; aP1 += 64; aP2 += 64; aP3 += 64;                               \
  bP0 += 64; bP1 += 64; bP2 += 64; bP3 += 64;                               \
} while (0)

#define LDA8(u, fi) (*(const i32x4*)(lds + (u) * 32768                      \
    + (wm * 8 + (fi)) * 1024 + laneoff))
#define LDB8(u, fj) (*(const i32x4*)(lds + (u) * 32768 + 16384              \
    + (wn * 8 + (fj)) * 1024 + laneoff))

// One window. u compile-time; AFC/BFC current frag sets; AFN/BFN next.
// dord: read frags(t+1); dostg: stage tile t+3; vmarg: 8 / 0 / -1 (none).
// SGB masks: MFMA=0x8, VMEM_READ=0x20, DS_READ=0x100.
#define WIN(u, AFC, BFC, AFN, BFN, dord, dostg, vmarg) do {                 \
  __builtin_amdgcn_s_setprio(1);                                            \
  if (dord) {                                                               \
    _Pragma("unroll") for (int i_ = 0; i_ < 8; ++i_)                        \
      AFN[i_] = LDA8(((u) + 1) & 3, i_);                                    \
    _Pragma("unroll") for (int j_ = 0; j_ < 8; ++j_)                        \
      BFN[j_] = LDB8(((u) + 1) & 3, j_);                                    \
  }                                                                         \
  if (dostg) STGL(((u) + 3) & 3);                                           \
  _Pragma("unroll") for (int i_ = 0; i_ < 8; ++i_)                          \
  _Pragma("unroll") for (int j_ = 0; j_ < 8; ++j_)                          \
    acc[i_][j_] = __builtin_amdgcn_mfma_i32_16x16x64_i8(                    \
        AFC[i_], BFC[j_], acc[i_][j_], 0, 0, 0);                            \
  __builtin_amdgcn_s_setprio(0);                                            \
  if ((dord) && (dostg)) {                                                  \
    SGB(0x100, 2); SGB(0x20, 1); SGB(0x8, 8);                               \
    SGB(0x100, 2); SGB(0x20, 1); SGB(0x8, 8);                               \
    SGB(0x100, 2); SGB(0x20, 1); SGB(0x8, 8);                               \
    SGB(0x100, 2); SGB(0x20, 1); SGB(0x8, 8);                               \
    SGB(0x100, 2); SGB(0x20, 1); SGB(0x8, 8);                               \
    SGB(0x100, 2); SGB(0x20, 1); SGB(0x8, 8);                               \
    SGB(0x100, 2); SGB(0x20, 1); SGB(0x8, 8);                               \
    SGB(0x100, 2); SGB(0x20, 1); SGB(0x8, 8);                               \
  }                                                                         \
  if ((vmarg) == 8) { WAITVM(8); } else if ((vmarg) == 0) { WAITVM(0); }    \
  BAR;                                                                      \
} while (0)

__global__ void __launch_bounds__(256, 1) gemm_i8_mega(
    const signed char* __restrict__ A, const signed char* __restrict__ Bw,
    const float* __restrict__ sx, const float* __restrict__ scale_p,
    const float* __restrict__ bias, float* __restrict__ out) {
  __shared__ __align__(16) char lds[131072];   // 4 bufs x (A 16K + B 16K)

  const int t      = threadIdx.x;        // 0..255
  const int lane   = t & 63;
  const int wave   = t >> 6;             // 0..3
  const int wm     = wave >> 1;          // 0..1  (row half: 128 rows)
  const int wn     = wave & 1;           // 0..1  (col half: 128 cols)
  const int lane15 = lane & 15;
  const int lh     = lane >> 4;          // 0..3

  // round-3/8-proven zero-conflict swizzled read offset (XOR, not '+').
  const int laneoff = (lane15 * 64 + lh * 16) ^ ((lane15 & 8) << 2);

  // round-8-proven stage decode (t 0..255 -> rows 0..63 of each chunk):
  const int ax = ((t >> 5) & 1) << 5;
  const int a0 = (t * 16) ^ ax;
  const int r0 = a0 >> 6;                // row 0..63 within chunk half
  const int cb = a0 & 63;                // K-byte within 64B row

  // XCD-aware swizzle: nwg = 512 (divisible by 8)
  const int bid   = blockIdx.x;
  const int wg    = (bid & 7) * 64 + (bid >> 3);
  const int ntile = wg & 15;             // 16 n-tiles
  const int mtile = wg >> 4;             // 32 m-tiles
  const int m0 = mtile * 256;
  const int n0 = ntile * 256;

  const char* Arow = (const char*)(A + (size_t)m0 * KDIM);
  const char* Brow = (const char*)(Bw + (size_t)n0 * KDIM);

  // advancing in-loop stage sources (start at tile 3: col byte 192)
  const char* aP0 = Arow + (size_t)r0 * 4096 + 192 + cb;
  const char* aP1 = Arow + (size_t)(r0 + 64) * 4096 + 192 + cb;
  const char* aP2 = Arow + (size_t)(r0 + 128) * 4096 + 192 + cb;
  const char* aP3 = Arow + (size_t)(r0 + 192) * 4096 + 192 + cb;
  const char* bP0 = Brow + (size_t)r0 * 4096 + 192 + cb;
  const char* bP1 = Brow + (size_t)(r0 + 64) * 4096 + 192 + cb;
  const char* bP2 = Brow + (size_t)(r0 + 128) * 4096 + 192 + cb;
  const char* bP3 = Brow + (size_t)(r0 + 192) * 4096 + 192 + cb;

  i32x4 acc[8][8] = {};
  i32x4 afE[8], afO[8], bfE[8], bfO[8];

  // Prologue: stage tiles 0,1,2 (24 GLL/thread).
  STGP(0);
  STGP(1);
  STGP(2);
  WAITVM(16);  // retire stage(0)
  BAR;
#pragma unroll
  for (int i_ = 0; i_ < 8; ++i_) afE[i_] = LDA8(0, i_);
#pragma unroll
  for (int j_ = 0; j_ < 8; ++j_) bfE[j_] = LDB8(0, j_);
  WAITVM(8);   // retire stage(1) -> buf1 valid for window 0's reads
  BAR;

  // Main: windows 0..59 (stage tiles 3..62), then tail 60..63.
#pragma unroll 1
  for (int tp = 0; tp < 15; ++tp) {
    WIN(0, afE, bfE, afO, bfO, 1, 1, 8);
    WIN(1, afO, bfO, afE, bfE, 1, 1, 8);
    WIN(2, afE, bfE, afO, bfO, 1, 1, 8);
    WIN(3, afO, bfO, afE, bfE, 1, 1, 8);
  }
  WIN(0, afE, bfE, afO, bfO, 1, 1, 8);   // t=60: stages tile 63 -> buf3
  WIN(1, afO, bfO, afE, bfE, 1, 0, 0);   // t=61: drain stage(63)
  WIN(2, afE, bfE, afO, bfO, 1, 0, -1);  // t=62: reads frags(63)
  WIN(3, afO, bfO, afE, bfE, 0, 0, -1);  // t=63: MFMA only

  // Epilogue: D layout col=lane&15, row=(lane>>4)*4+q (shape-determined,
  // dtype-independent — m89/m121-128). out = acc * sx[row]*sw + bias.
  const float sw = scale_p[0];
  float bv[8];
#pragma unroll
  for (int j = 0; j < 8; ++j) bv[j] = bias[n0 + wn * 128 + j * 16 + lane15];
#pragma unroll
  for (int fi = 0; fi < 8; ++fi) {
    const int rowb = m0 + wm * 128 + fi * 16 + lh * 4;
    float sxq[4];
#pragma unroll
    for (int q = 0; q < 4; ++q) sxq[q] = sx[rowb + q] * sw;
#pragma unroll
    for (int fj = 0; fj < 8; ++fj) {
      const int col = n0 + wn * 128 + fj * 16 + lane15;
#pragma unroll
      for (int q = 0; q < 4; ++q)
        out[(size_t)(rowb + q) * NDIM + col] = (float)acc[fi][fj][q] * sxq[q] + bv[fj];
    }
  }
}

// ---------------- fallback: m97-style bf16 reg-staging (ws too small) ----------------
constexpr int FTILE = 128;
constexpr int FBK   = 64;

__global__ void __launch_bounds__(256) gemm_raw(
    const float* __restrict__ X, const int* __restrict__ W,
    const float* __restrict__ scale_p, const float* __restrict__ bias,
    float* __restrict__ out) {
  __shared__ short As[FTILE * FBK];
  __shared__ short Bs[FTILE * FBK];

  const int t      = threadIdx.x;
  const int lane   = t & 63;
  const int wave   = t >> 6;
  const int wm     = wave >> 1;
  const int wn     = wave & 1;
  const int lane15   = lane & 15;
  const int laneHalf = lane >> 4;

  const int bid   = blockIdx.x;
  const int wg    = (bid & 7) * 256 + (bid >> 3);
  const int ntile = wg & 31;
  const int mtile = wg >> 5;
  const int m0 = mtile * FTILE;
  const int n0 = ntile * FTILE;

  f32x4 acc[4][4] = {};

  for (int k0 = 0; k0 < KDIM; k0 += FBK) {
    __syncthreads();
#pragma unroll
    for (int r = 0; r < 8; ++r) {
      const int f   = r * 256 + t;
      const int row = f >> 4;
      const int c4  = (f & 15) * 4;
      f32x4 v = *(const f32x4*)(X + (size_t)(m0 + row) * KDIM + (k0 + c4));
      s16x4 h;
#pragma unroll
      for (int j = 0; j < 4; ++j) h[j] = f32_to_bf16_rn(v[j]);
      *(s16x4*)&As[row * FBK + c4] = h;

      i32x4 wv = *(const i32x4*)(W + (size_t)(n0 + row) * KDIM + (k0 + c4));
      s16x4 hw;
#pragma unroll
      for (int j = 0; j < 4; ++j) hw[j] = f32_to_bf16_rn((float)wv[j]);
      *(s16x4*)&Bs[row * FBK + c4] = hw;
    }
    __syncthreads();

#pragma unroll
    for (int kk = 0; kk < FBK; kk += 32) {
      const int kb = kk + laneHalf * 8;
      using s16x8f = __attribute__((ext_vector_type(8))) short;
      s16x8f af[4], bf[4];
#pragma unroll
      for (int i = 0; i < 4; ++i) {
        af[i] = *(const s16x8f*)&As[(wm * 64 + i * 16 + lane15) * FBK + kb];
        bf[i] = *(const s16x8f*)&Bs[(wn * 64 + i * 16 + lane15) * FBK + kb];
      }
#pragma unroll
      for (int i = 0; i < 4; ++i)
#pragma unroll
        for (int j = 0; j < 4; ++j)
          acc[i][j] = __builtin_amdgcn_mfma_f32_16x16x32_bf16(af[i], bf[j], acc[i][j], 0, 0, 0);
    }
  }

  const float s = scale_p[0];
#pragma unroll
  for (int j = 0; j < 4; ++j) {
    const int col = n0 + wn * 64 + j * 16 + lane15;
    const float bv = bias[col];
#pragma unroll
    for (int i = 0; i < 4; ++i) {
      const int row = m0 + wm * 64 + i * 16 + laneHalf * 4;
#pragma unroll
      for (int q = 0; q < 4; ++q)
        out[(size_t)(row + q) * NDIM + col] = acc[i][j][q] * s + bv;
    }
  }
}

extern "C" void kernel_launch(void* const* d_in, const int* in_sizes, int n_in,
                              void* d_out, int out_size, void* d_ws, size_t ws_size,
                              hipStream_t stream) {
  const float* x     = (const float*)d_in[0];
  const int*   w     = (const int*)d_in[1];    // integer inputs materialize as int32
  const float* scale = (const float*)d_in[2];
  const float* bias  = (const float*)d_in[3];
  float* out = (float*)d_out;

  const size_t a_bytes = (size_t)MDIM * KDIM;            // 33,554,432 (i8)
  const size_t b_bytes = (size_t)NDIM * KDIM;            // 16,777,216 (i8)
  const size_t need    = a_bytes + b_bytes + MDIM * 4;   // + sx floats

  if (ws_size >= need) {
    signed char* Ai8 = (signed char*)d_ws;
    signed char* Bi8 = Ai8 + a_bytes;
    float*       sxp = (float*)(Bi8 + b_bytes);
    quant_x_kernel<<<MDIM, 256, 0, stream>>>(x, Ai8, sxp);
    quant_w_kernel<<<4096, 256, 0, stream>>>(w, Bi8, (int)(b_bytes / 16));
    const int nwg = (MDIM / 256) * (NDIM / 256);  // 32*16 = 512
    gemm_i8_mega<<<nwg, 256, 0, stream>>>(Ai8, Bi8, sxp, scale, bias, out);
  } else {
    const int nwg = (MDIM / FTILE) * (NDIM / FTILE);  // 2048
    gemm_raw<<<nwg, 256, 0, stream>>>(x, w, scale, bias, out);
  }
}

// Round 17
// 182.257 us; speedup vs baseline: 1.0250x; 1.0250x over previous
//
#include <hip/hip_runtime.h>
#include <stdint.h>
#include <stddef.h>

// Problem geometry (B=4, S=2048, DIN=4096, DOUT=4096)
constexpr int MDIM = 8192;   // B*S
constexpr int NDIM = 4096;   // DOUT
constexpr int KDIM = 4096;   // DIN

using f32x4 = __attribute__((ext_vector_type(4))) float;
using s16x4 = __attribute__((ext_vector_type(4))) short;
using i32x4 = __attribute__((ext_vector_type(4))) int;

__device__ __forceinline__ short f32_to_bf16_rn(float f) {
  union { float f; uint32_t u; } v; v.f = f;
  uint32_t r = (v.u + 0x7FFFu + ((v.u >> 16) & 1u)) >> 16;  // RTN-even
  return (short)(uint16_t)r;
}

// ---------------- prepass 1: x f32 -> i8, per-row symmetric scale (row-major) ----
__global__ void __launch_bounds__(256) quant_x_kernel(const float* __restrict__ in,
                                                      signed char* __restrict__ out,
                                                      float* __restrict__ sx) {
  const int row = blockIdx.x;
  const int t   = threadIdx.x;
  const float* rp = in + (size_t)row * KDIM;
  f32x4 v[4];
  float m = 0.0f;
#pragma unroll
  for (int j = 0; j < 4; ++j) {
    v[j] = *(const f32x4*)(rp + t * 16 + j * 4);
#pragma unroll
    for (int e = 0; e < 4; ++e) m = fmaxf(m, __builtin_fabsf(v[j][e]));
  }
#pragma unroll
  for (int off = 32; off > 0; off >>= 1) m = fmaxf(m, __shfl_xor(m, off, 64));
  __shared__ float wmax[4];
  const int wv = t >> 6, ln = t & 63;
  if (ln == 0) wmax[wv] = m;
  __syncthreads();
  m = fmaxf(fmaxf(wmax[0], wmax[1]), fmaxf(wmax[2], wmax[3]));
  const float inv = (m > 0.0f) ? (127.0f / m) : 0.0f;
  if (t == 0) sx[row] = m * (1.0f / 127.0f);
  i32x4 o;
#pragma unroll
  for (int j = 0; j < 4; ++j) {
    int b[4];
#pragma unroll
    for (int e = 0; e < 4; ++e) {
      int q = (int)rintf(v[j][e] * inv);
      q = q < -127 ? -127 : (q > 127 ? 127 : q);
      b[e] = q & 255;
    }
    o[j] = b[0] | (b[1] << 8) | (b[2] << 16) | (b[3] << 24);
  }
  *(i32x4*)(out + (size_t)row * KDIM + t * 16) = o;
}

// ---------------- prepass 2: weight int32 -> i8 (exact, low-byte pack) ----------------
__global__ void __launch_bounds__(256) quant_w_kernel(const int* __restrict__ in,
                                                      signed char* __restrict__ out, int n16) {
  int i = blockIdx.x * 256 + threadIdx.x;
  const int stride = gridDim.x * 256;
  for (; i < n16; i += stride) {
    const i32x4* p = (const i32x4*)(in + (size_t)i * 16);
    i32x4 o;
#pragma unroll
    for (int j = 0; j < 4; ++j) {
      i32x4 a = p[j];
      o[j] = (a[0] & 255) | ((a[1] & 255) << 8) | ((a[2] & 255) << 16) | ((a[3] & 255) << 24);
    }
    *(i32x4*)(out + (size_t)i * 16) = o;
  }
}

// =====================================================================
// 256x256 i8 GEMM = round-11 ring pipeline + T19 interleave (ROUND-15
// BEST-KNOWN CONFIGURATION, restored verbatim after r16 regression).
// sched_group_barrier pins each window's emission to
//   4 x { 3 DS_READ , 1 VMEM_READ(GLL) , 8 MFMA }
// Mechanism: reads are for t+1 (off critical path); spacing them among
// MFMAs keeps the per-CU LDS queue shallow -> no in-order issue-stall ->
// LDS unit and matrix pipe overlap (measured +5% over r11; best of 8
// structurally-distinct i8 schedules r8-r16).
//   out = (i32 acc) * sx[row] * s_w + bias[col]
// =====================================================================

#define BAR asm volatile("s_barrier" ::: "memory")
#define WAITVM(n) asm volatile("s_waitcnt vmcnt(" #n ")" ::: "memory")
#define SGB(mask, n) __builtin_amdgcn_sched_group_barrier((mask), (n), 0)

#define GLL(src, dst) __builtin_amdgcn_global_load_lds(                     \
    (const __attribute__((address_space(1))) void*)(src),                   \
    (__attribute__((address_space(3))) void*)(dst), 16, 0, 0)

// prologue: stage tile tau into buf tau (tau = 0,1,2)
#define STGP(tau) do {                                                      \
  GLL(Arow + (size_t)r0 * 4096 + (tau) * 64 + cb,                           \
      lds + (tau) * 32768 + t * 16);                                        \
  GLL(Arow + (size_t)(128 + r0) * 4096 + (tau) * 64 + cb,                   \
      lds + (tau) * 32768 + 8192 + t * 16);                                 \
  GLL(Brow + (size_t)r0 * 4096 + (tau) * 64 + cb,                           \
      lds + (tau) * 32768 + 16384 + t * 16);                                \
  GLL(Brow + (size_t)(128 + r0) * 4096 + (tau) * 64 + cb,                   \
      lds + (tau) * 32768 + 16384 + 8192 + t * 16);                         \
} while (0)

// in-loop: advancing per-thread source pointers (start at tile 3 cols)
#define STGL(u3) do {                                                       \
  GLL(aSrc0, lds + (u3) * 32768 + t * 16);                                  \
  GLL(aSrc1, lds + (u3) * 32768 + 8192 + t * 16);                           \
  GLL(bSrc0, lds + (u3) * 32768 + 16384 + t * 16);                          \
  GLL(bSrc1, lds + (u3) * 32768 + 16384 + 8192 + t * 16);                   \
  aSrc0 += 64; aSrc1 += 64; bSrc0 += 64; bSrc1 += 64;                       \
} while (0)

#define LDA8(u, fi) (*(const i32x4*)(lds + (u) * 32768                      \
    + (wm * 8 + (fi)) * 1024 + laneoff))
#define LDB8(u, j)  (*(const i32x4*)(lds + (u) * 32768 + 16384              \
    + (wn * 4 + (j)) * 1024 + laneoff))

// One window. u compile-time; AFC/BFC = current frag set, AFN/BFN = next.
// dord: read frags(t+1); dostg: stage tile t+3; vmarg: 4 / 0 / -1 (none).
// SGB masks (m137/LLVM): MFMA=0x8, VMEM_READ=0x20, DS_READ=0x100.
#define WIN(u, AFC, BFC, AFN, BFN, dord, dostg, vmarg) do {                 \
  __builtin_amdgcn_s_setprio(1);                                            \
  if (dord) {                                                               \
    _Pragma("unroll") for (int i_ = 0; i_ < 8; ++i_)                        \
      AFN[i_] = LDA8(((u) + 1) & 3, i_);                                    \
    _Pragma("unroll") for (int j_ = 0; j_ < 4; ++j_)                        \
      BFN[j_] = LDB8(((u) + 1) & 3, j_);                                    \
  }                                                                         \
  if (dostg) STGL(((u) + 3) & 3);                                           \
  _Pragma("unroll") for (int i_ = 0; i_ < 8; ++i_)                          \
  _Pragma("unroll") for (int j_ = 0; j_ < 4; ++j_)                          \
    acc[i_][j_] = __builtin_amdgcn_mfma_i32_16x16x64_i8(                    \
        AFC[i_], BFC[j_], acc[i_][j_], 0, 0, 0);                            \
  __builtin_amdgcn_s_setprio(0);                                            \
  if ((dord) && (dostg)) {                                                  \
    SGB(0x100, 3); SGB(0x20, 1); SGB(0x8, 8);                               \
    SGB(0x100, 3); SGB(0x20, 1); SGB(0x8, 8);                               \
    SGB(0x100, 3); SGB(0x20, 1); SGB(0x8, 8);                               \
    SGB(0x100, 3); SGB(0x20, 1); SGB(0x8, 8);                               \
  }                                                                         \
  if ((vmarg) == 4) { WAITVM(4); } else if ((vmarg) == 0) { WAITVM(0); }    \
  BAR;                                                                      \
} while (0)

__global__ void __launch_bounds__(512, 1) gemm_i8_ring_ilv(
    const signed char* __restrict__ A, const signed char* __restrict__ Bw,
    const float* __restrict__ sx, const float* __restrict__ scale_p,
    const float* __restrict__ bias, float* __restrict__ out) {
  __shared__ __align__(16) char lds[131072];   // 4 bufs x (A 16K + B 16K)

  const int t      = threadIdx.x;        // 0..511
  const int lane   = t & 63;
  const int wave   = t >> 6;
  const int wm     = wave >> 2;          // 0..1  (row half: 128 rows)
  const int wn     = wave & 3;           // 0..3  (col quarter: 64 cols)
  const int lane15 = lane & 15;
  const int lh     = lane >> 4;          // 0..3

  // round-3/8-proven zero-conflict swizzled read offset (XOR, not '+').
  const int laneoff = (lane15 * 64 + lh * 16) ^ ((lane15 & 8) << 2);

  // round-8-proven stage decode per 8-KB chunk:
  const int ax = ((t >> 5) & 1) << 5;
  const int a0 = (t * 16) ^ ax;
  const int r0 = a0 >> 6;                // row 0..127 within chunk
  const int cb = a0 & 63;                // K-byte within 64B row

  // XCD-aware swizzle: nwg = 512 (divisible by 8)
  const int bid   = blockIdx.x;
  const int wg    = (bid & 7) * 64 + (bid >> 3);
  const int ntile = wg & 15;             // 16 n-tiles
  const int mtile = wg >> 4;             // 32 m-tiles
  const int m0 = mtile * 256;
  const int n0 = ntile * 256;

  const char* Arow = (const char*)(A + (size_t)m0 * KDIM);
  const char* Brow = (const char*)(Bw + (size_t)n0 * KDIM);

  const char* aSrc0 = Arow + (size_t)r0 * 4096 + 192 + cb;
  const char* aSrc1 = Arow + (size_t)(128 + r0) * 4096 + 192 + cb;
  const char* bSrc0 = Brow + (size_t)r0 * 4096 + 192 + cb;
  const char* bSrc1 = Brow + (size_t)(128 + r0) * 4096 + 192 + cb;

  i32x4 acc[8][4] = {};
  i32x4 afE[8], afO[8], bfE[4], bfO[4];

  // Prologue: stage tiles 0,1,2 (12 GLL/thread).
  STGP(0);
  STGP(1);
  STGP(2);
  WAITVM(8);   // retire stage(0)
  BAR;
#pragma unroll
  for (int i_ = 0; i_ < 8; ++i_) afE[i_] = LDA8(0, i_);
#pragma unroll
  for (int j_ = 0; j_ < 4; ++j_) bfE[j_] = LDB8(0, j_);
  WAITVM(4);   // retire stage(1) -> buf1 valid for window 0's reads
  BAR;

  // Main: windows 0..59 (stage tiles 3..62), then tail 60..63.
#pragma unroll 1
  for (int tp = 0; tp < 15; ++tp) {
    WIN(0, afE, bfE, afO, bfO, 1, 1, 4);
    WIN(1, afO, bfO, afE, bfE, 1, 1, 4);
    WIN(2, afE, bfE, afO, bfO, 1, 1, 4);
    WIN(3, afO, bfO, afE, bfE, 1, 1, 4);
  }
  WIN(0, afE, bfE, afO, bfO, 1, 1, 4);   // t=60: stages tile 63
  WIN(1, afO, bfO, afE, bfE, 1, 0, 0);   // t=61: drain stage(63)
  WIN(2, afE, bfE, afO, bfO, 1, 0, -1);  // t=62: reads frags(63)
  WIN(3, afO, bfO, afE, bfE, 0, 0, -1);  // t=63: MFMA only

  // Epilogue: D layout col=lane&15, row=(lane>>4)*4+q (shape-determined,
  // dtype-independent — m89/m121-128). out = acc * sx[row]*sw + bias.
  const float sw = scale_p[0];
  float bv[4];
#pragma unroll
  for (int j = 0; j < 4; ++j) bv[j] = bias[n0 + wn * 64 + j * 16 + lane15];
#pragma unroll
  for (int i = 0; i < 8; ++i) {
    const int rowb = m0 + wm * 128 + i * 16 + lh * 4;
    float sxq[4];
#pragma unroll
    for (int q = 0; q < 4; ++q) sxq[q] = sx[rowb + q] * sw;
#pragma unroll
    for (int j = 0; j < 4; ++j) {
      const int col = n0 + wn * 64 + j * 16 + lane15;
#pragma unroll
      for (int q = 0; q < 4; ++q)
        out[(size_t)(rowb + q) * NDIM + col] = (float)acc[i][j][q] * sxq[q] + bv[j];
    }
  }
}

// ---------------- fallback: m97-style bf16 reg-staging (ws too small) ----------------
constexpr int FTILE = 128;
constexpr int FBK   = 64;

__global__ void __launch_bounds__(256) gemm_raw(
    const float* __restrict__ X, const int* __restrict__ W,
    const float* __restrict__ scale_p, const float* __restrict__ bias,
    float* __restrict__ out) {
  __shared__ short As[FTILE * FBK];
  __shared__ short Bs[FTILE * FBK];

  const int t      = threadIdx.x;
  const int lane   = t & 63;
  const int wave   = t >> 6;
  const int wm     = wave >> 1;
  const int wn     = wave & 1;
  const int lane15   = lane & 15;
  const int laneHalf = lane >> 4;

  const int bid   = blockIdx.x;
  const int wg    = (bid & 7) * 256 + (bid >> 3);
  const int ntile = wg & 31;
  const int mtile = wg >> 5;
  const int m0 = mtile * FTILE;
  const int n0 = ntile * FTILE;

  f32x4 acc[4][4] = {};

  for (int k0 = 0; k0 < KDIM; k0 += FBK) {
    __syncthreads();
#pragma unroll
    for (int r = 0; r < 8; ++r) {
      const int f   = r * 256 + t;
      const int row = f >> 4;
      const int c4  = (f & 15) * 4;
      f32x4 v = *(const f32x4*)(X + (size_t)(m0 + row) * KDIM + (k0 + c4));
      s16x4 h;
#pragma unroll
      for (int j = 0; j < 4; ++j) h[j] = f32_to_bf16_rn(v[j]);
      *(s16x4*)&As[row * FBK + c4] = h;

      i32x4 wv = *(const i32x4*)(W + (size_t)(n0 + row) * KDIM + (k0 + c4));
      s16x4 hw;
#pragma unroll
      for (int j = 0; j < 4; ++j) hw[j] = f32_to_bf16_rn((float)wv[j]);
      *(s16x4*)&Bs[row * FBK + c4] = hw;
    }
    __syncthreads();

#pragma unroll
    for (int kk = 0; kk < FBK; kk += 32) {
      const int kb = kk + laneHalf * 8;
      using s16x8f = __attribute__((ext_vector_type(8))) short;
      s16x8f af[4], bf[4];
#pragma unroll
      for (int i = 0; i < 4; ++i) {
        af[i] = *(const s16x8f*)&As[(wm * 64 + i * 16 + lane15) * FBK + kb];
        bf[i] = *(const s16x8f*)&Bs[(wn * 64 + i * 16 + lane15) * FBK + kb];
      }
#pragma unroll
      for (int i = 0; i < 4; ++i)
#pragma unroll
        for (int j = 0; j < 4; ++j)
          acc[i][j] = __builtin_amdgcn_mfma_f32_16x16x32_bf16(af[i], bf[j], acc[i][j], 0, 0, 0);
    }
  }

  const float s = scale_p[0];
#pragma unroll
  for (int j = 0; j < 4; ++j) {
    const int col = n0 + wn * 64 + j * 16 + lane15;
    const float bv = bias[col];
#pragma unroll
    for (int i = 0; i < 4; ++i) {
      const int row = m0 + wm * 64 + i * 16 + laneHalf * 4;
#pragma unroll
      for (int q = 0; q < 4; ++q)
        out[(size_t)(row + q) * NDIM + col] = acc[i][j][q] * s + bv;
    }
  }
}

extern "C" void kernel_launch(void* const* d_in, const int* in_sizes, int n_in,
                              void* d_out, int out_size, void* d_ws, size_t ws_size,
                              hipStream_t stream) {
  const float* x     = (const float*)d_in[0];
  const int*   w     = (const int*)d_in[1];    // integer inputs materialize as int32
  const float* scale = (const float*)d_in[2];
  const float* bias  = (const float*)d_in[3];
  float* out = (float*)d_out;

  const size_t a_bytes = (size_t)MDIM * KDIM;            // 33,554,432 (i8)
  const size_t b_bytes = (size_t)NDIM * KDIM;            // 16,777,216 (i8)
  const size_t need    = a_bytes + b_bytes + MDIM * 4;   // + sx floats

  if (ws_size >= need) {
    signed char* Ai8 = (signed char*)d_ws;
    signed char* Bi8 = Ai8 + a_bytes;
    float*       sxp = (float*)(Bi8 + b_bytes);
    quant_x_kernel<<<MDIM, 256, 0, stream>>>(x, Ai8, sxp);
    quant_w_kernel<<<4096, 256, 0, stream>>>(w, Bi8, (int)(b_bytes / 16));
    const int nwg = (MDIM / 256) * (NDIM / 256);  // 32*16 = 512
    gemm_i8_ring_ilv<<<nwg, 512, 0, stream>>>(Ai8, Bi8, sxp, scale, bias, out);
  } else {
    const int nwg = (MDIM / FTILE) * (NDIM / FTILE);  // 2048
    gemm_raw<<<nwg, 256, 0, stream>>>(x, w, scale, bias, out);
  }
}